// Round 6
// baseline (101.943 us; speedup 1.0000x reference)
//
#include <hip/hip_runtime.h>
#include <hip/hip_bf16.h>

#define D 512
#define NWAY 64
#define KSHOT 16
#define NQ 8192
#define BM 64

typedef __bf16 bf16_t;
typedef __bf16 bf16x8_t __attribute__((ext_vector_type(8)));
typedef __bf16 bf16x4_t __attribute__((ext_vector_type(4)));
typedef float  f32x4    __attribute__((ext_vector_type(4)));

typedef __attribute__((address_space(1))) const void gv_t;
typedef __attribute__((address_space(3))) void lv_t;
__device__ __forceinline__ void ld16(const void* g, void* l) {
    __builtin_amdgcn_global_load_lds((gv_t*)g, (lv_t*)l, 16, 0, 0);
}

// Bsw: [ck(8)][n(512)][seg(8)] bf16, off = ck*32768 + n*64 + ((s^(n&7))*8)
// Psw: [c(64)][pos(64)][e(8)] bf16, off = c*512 + pos*8 + (k&7),
//   pos = (s&~7)|((s&7)^(c&7)), s = k>>3  (row-swizzled, staged verbatim)

// ---------------------------------------------------------------- K_PREP
// (unchanged from R5 — proven at 99.3)
// blocks 0..255: P blocks (c=b>>2, jq=b&3): P_c[j] = cm_c.W_j + b_j -> Psw bf16
// blocks 256..383: W -> bf16 swizzled into Bsw (4 rows/block)
__global__ __launch_bounds__(256) void k_prep(
    const float* __restrict__ sup, const float* __restrict__ W,
    const float* __restrict__ bias, bf16_t* __restrict__ Bsw,
    bf16_t* __restrict__ Psw)
{
    const int b = blockIdx.x, t = threadIdx.x;

    if (b < 256) {                         // ---- P blocks
        const int c = b >> 2, jq = b & 3;
        __shared__ __align__(16) float cm[D];
        {   // cm_c = mean over shots (float2 per thread)
            const int d = t * 2;
            float sx = 0.f, sy = 0.f;
#pragma unroll
            for (int j = 0; j < KSHOT; ++j) {
                float2 v = *(const float2*)(sup + (size_t)(c * KSHOT + j) * D + d);
                sx += v.x; sy += v.y;
            }
            cm[d] = sx * (1.0f / KSHOT); cm[d + 1] = sy * (1.0f / KSHOT);
        }
        __syncthreads();
        const int j = jq * 128 + (t >> 1);
        const int half = t & 1;
        const f32x4* wr = (const f32x4*)(W + (size_t)j * D + half * 256);
        const f32x4* cr = (const f32x4*)(cm + half * 256);
        float s = 0.f;
#pragma unroll 8
        for (int i = 0; i < 64; ++i) {
            f32x4 a = cr[i], wv = wr[i];
            s += a[0]*wv[0] + a[1]*wv[1] + a[2]*wv[2] + a[3]*wv[3];
        }
        s += __shfl_xor(s, 1);
        if (!half) {
            const float v = s + bias[j];
            const int sP = j >> 3;
            const int pos = (sP & ~7) | ((sP & 7) ^ (c & 7));
            Psw[c * 512 + pos * 8 + (j & 7)] = (bf16_t)v;
        }
        return;
    }

    {                                      // ---- W conversion, 4 rows/block
        const int n = (b - 256) * 4 + (t >> 6);
        const int sl = t & 63;
        const f32x4* wp = (const f32x4*)(W + (size_t)n * D + sl * 8);
        f32x4 v0 = wp[0], v1 = wp[1];
        bf16x8_t hv = { (bf16_t)v0[0], (bf16_t)v0[1], (bf16_t)v0[2], (bf16_t)v0[3],
                        (bf16_t)v1[0], (bf16_t)v1[1], (bf16_t)v1[2], (bf16_t)v1[3] };
        const int ck = sl >> 3, s = sl & 7;
        *(bf16x8_t*)(Bsw + (size_t)ck * 32768 + n * 64 + ((s ^ (n & 7)) * 8)) = hv;
    }
}

// ---------------------------------------------------------------- K_MAIN
// 128 blocks x 512 thr (BM=64): halves total L2->LDS DMA traffic vs BM=32.
// 8 chunks, double-buffered DMA; chunk-7 stage slot DMAs the 64KB Psw tile
// into Bb[0]. Epilogue: eq transpose -> Bb[1] (64KB), cross-GEMM with FULL
// K per wave (no cross-wave exchange), dist = qt - 2*cross + ||p~||^2.
__global__ __launch_bounds__(512, 2) void k_main(
    const float* __restrict__ query, const bf16_t* __restrict__ Bsw,
    const bf16_t* __restrict__ Psw, const float* __restrict__ bias,
    float* __restrict__ out)
{
    __shared__ __align__(16) bf16_t Bb[2][32768]; // 131,072 B
    __shared__ __align__(16) bf16_t Ab[2][4096];  //  16,384 B
    __shared__ float qln[4][BM];    //   1,024 B
    __shared__ float phs[NWAY];     //     256 B
    __shared__ float bs[512];       //   2,048 B  (total 150,784 B -> 1/CU)

    const int t = threadIdx.x, bm = blockIdx.x;
    bs[t] = bias[t];

    const int l = t & 63, w = t >> 6;
    const int wm = w & 1, wn = w >> 1;
    const int r15 = l & 15, quad = l >> 4;

    const int xt0 = ((quad ^ (r15 & 7)) * 8);
    const int xt1 = (((4 + quad) ^ (r15 & 7)) * 8);
    const int aoff0 = (wm * 32 + r15) * 64;        // row-tile 0 of this wm
    const int aoff1 = (wm * 32 + 16 + r15) * 64;   // row-tile 1
    const int boff = (wn * 128 + r15) * 64;

    // ---- A preload: thread owns row am (0..63), seg as (0..7), all 8 chunks
    const int am = t >> 3;
    const int as = t & 7;
    const int a_lds = am * 64 + ((as ^ (am & 7)) * 8);
    const float* aqp = query + (size_t)(bm * BM + am) * D + as * 8;

    bf16x8_t areg[8];
#pragma unroll
    for (int ck = 0; ck < 8; ++ck) {
        f32x4 v0 = *(const f32x4*)(aqp + ck * 64);
        f32x4 v1 = *(const f32x4*)(aqp + ck * 64 + 4);
        areg[ck] = (bf16x8_t){ (bf16_t)v0[0], (bf16_t)v0[1], (bf16_t)v0[2], (bf16_t)v0[3],
                               (bf16_t)v1[0], (bf16_t)v1[1], (bf16_t)v1[2], (bf16_t)v1[3] };
    }

    f32x4 acc[2][8];
#pragma unroll
    for (int rt = 0; rt < 2; ++rt)
#pragma unroll
        for (int i = 0; i < 8; ++i) acc[rt][i] = (f32x4){0.f, 0.f, 0.f, 0.f};

    // ---- prologue: stage chunk 0 into buffer 0
    {
#pragma unroll
        for (int i = 0; i < 8; ++i) {
            const int off = t * 8 + i * 4096;
            ld16(Bsw + off, &Bb[0][off]);
        }
        *(bf16x8_t*)(&Ab[0][a_lds]) = areg[0];
    }
    __syncthreads();   // drains vmcnt(0)+lgkmcnt(0): chunk 0 ready

    // ---- main loop: issue-next / compute-current / one barrier per chunk
#pragma unroll
    for (int ck = 0; ck < 8; ++ck) {
        const int cur = ck & 1;
        if (ck < 7) {
            const int nxt = cur ^ 1;
            const size_t sb = (size_t)(ck + 1) * 32768;
#pragma unroll
            for (int i = 0; i < 8; ++i) {
                const int off = t * 8 + i * 4096;
                ld16(Bsw + sb + off, &Bb[nxt][off]);
            }
            *(bf16x8_t*)(&Ab[nxt][a_lds]) = areg[ck + 1];
        } else {
            // chunk-7 stage slot: DMA the P tile into Bb[0] (chunk-6 reads
            // of Bb[0] completed at the ck==6 barrier; chunk 7 uses Bb[1])
#pragma unroll
            for (int i = 0; i < 8; ++i) {
                const int off = t * 8 + i * 4096;
                ld16(Psw + off, &Bb[0][off]);
            }
        }

        bf16x8_t a00 = *(const bf16x8_t*)(&Ab[cur][aoff0 + xt0]);
        bf16x8_t a01 = *(const bf16x8_t*)(&Ab[cur][aoff0 + xt1]);
        bf16x8_t a10 = *(const bf16x8_t*)(&Ab[cur][aoff1 + xt0]);
        bf16x8_t a11 = *(const bf16x8_t*)(&Ab[cur][aoff1 + xt1]);
#pragma unroll
        for (int tt = 0; tt < 8; ++tt) {
            bf16x8_t b0 = *(const bf16x8_t*)(&Bb[cur][boff + tt * 1024 + xt0]);
            bf16x8_t b1 = *(const bf16x8_t*)(&Bb[cur][boff + tt * 1024 + xt1]);
            acc[0][tt] = __builtin_amdgcn_mfma_f32_16x16x32_bf16(a00, b0, acc[0][tt], 0, 0, 0);
            acc[0][tt] = __builtin_amdgcn_mfma_f32_16x16x32_bf16(a01, b1, acc[0][tt], 0, 0, 0);
            acc[1][tt] = __builtin_amdgcn_mfma_f32_16x16x32_bf16(a10, b0, acc[1][tt], 0, 0, 0);
            acc[1][tt] = __builtin_amdgcn_mfma_f32_16x16x32_bf16(a11, b1, acc[1][tt], 0, 0, 0);
        }

        if (ck < 7) __syncthreads();
    }
    __syncthreads();   // drains P DMA; all chunk-7 reads of Bb[1] done

    // ---- epilogue part 1: eq = acc + bias -> qt partials + E' transpose ----
    // E' (64 rows x 512 k, bf16, row-swizzled) = all of Bb[1]
    bf16_t* Ex = &Bb[1][0];
    float qp[2][4] = {{0.f,0.f,0.f,0.f},{0.f,0.f,0.f,0.f}};
#pragma unroll
    for (int tt = 0; tt < 8; ++tt) {
        const int k = wn * 128 + tt * 16 + r15;
        const int s = k >> 3, klo = k & 7;
        const float bv = bs[k];
#pragma unroll
        for (int rt = 0; rt < 2; ++rt)
#pragma unroll
        for (int reg = 0; reg < 4; ++reg) {
            const int row = wm * 32 + rt * 16 + quad * 4 + reg;
            const float v = acc[rt][tt][reg] + bv;
            qp[rt][reg] += v * v;
            const int pos = (s & ~7) | ((s & 7) ^ (row & 7));
            Ex[row * 512 + pos * 8 + klo] = (bf16_t)v;
        }
    }
#pragma unroll
    for (int rt = 0; rt < 2; ++rt)
#pragma unroll
    for (int reg = 0; reg < 4; ++reg) {
        float s = qp[rt][reg];
        s += __shfl_xor(s, 1); s += __shfl_xor(s, 2);
        s += __shfl_xor(s, 4); s += __shfl_xor(s, 8);
        if (r15 == 0) qln[wn][wm * 32 + rt * 16 + quad * 4 + reg] = s;
    }

    // ---- ||p~||^2 from the staged bf16 P tile (swizzle-invariant) ----
    if (t < NWAY) {
        const bf16_t* pr = &Bb[0][t * 512];
        float s2 = 0.f;
#pragma unroll
        for (int i = 0; i < 64; ++i) {
            bf16x8_t v = *(const bf16x8_t*)(pr + i * 8);
#pragma unroll
            for (int e = 0; e < 8; ++e) { float f = (float)v[e]; s2 += f * f; }
        }
        phs[t] = s2;
    }
    __syncthreads();

    // ---- epilogue part 2: cross-GEMM C[64x64] = eq . P^T, full K/wave ----
    // wave w: row-tile ert = w>>1 (16 rows), class-tiles ecg*2 + {0,1}
    const int ert = w >> 1, ecg = w & 1;
    f32x4 cacc[2];
    cacc[0] = (f32x4){0.f, 0.f, 0.f, 0.f};
    cacc[1] = (f32x4){0.f, 0.f, 0.f, 0.f};
    const bf16_t* Pl = &Bb[0][0];
#pragma unroll
    for (int kk = 0; kk < 16; ++kk) {
        const int s = kk * 4 + quad;                      // k>>3
        const int posA = (s & ~7) | ((s & 7) ^ (r15 & 7)); // row&7 == r15&7
        bf16x8_t af = *(const bf16x8_t*)(Ex + (ert * 16 + r15) * 512 + posA * 8);
#pragma unroll
        for (int j = 0; j < 2; ++j) {
            bf16x8_t bf = *(const bf16x8_t*)(Pl + ((ecg * 2 + j) * 16 + r15) * 512 + posA * 8);
            cacc[j] = __builtin_amdgcn_mfma_f32_16x16x32_bf16(af, bf, cacc[j], 0, 0, 0);
        }
    }

    // ---- write dists: qt - 2*cross + ||p~||^2 ----
#pragma unroll
    for (int reg = 0; reg < 4; ++reg) {
        const int row_local = ert * 16 + quad * 4 + reg;
        const float qt = qln[0][row_local] + qln[1][row_local] +
                         qln[2][row_local] + qln[3][row_local];
        const int rowg = bm * BM + row_local;
#pragma unroll
        for (int j = 0; j < 2; ++j) {
            const int c = (ecg * 2 + j) * 16 + r15;
            out[(size_t)rowg * NWAY + c] = qt + phs[c] - 2.0f * cacc[j][reg];
        }
    }
}

// ---------------------------------------------------------------- launch
extern "C" void kernel_launch(void* const* d_in, const int* in_sizes, int n_in,
                              void* d_out, int out_size, void* d_ws, size_t ws_size,
                              hipStream_t stream)
{
    const float* support = (const float*)d_in[0];
    const float* query   = (const float*)d_in[1];
    const float* W       = (const float*)d_in[2];
    const float* bias    = (const float*)d_in[3];
    float* out = (float*)d_out;

    char* ws = (char*)d_ws;
    bf16_t* Bsw = (bf16_t*)ws;                    // 524,288 B
    bf16_t* Psw = (bf16_t*)(ws + 524288);         //  65,536 B

    k_prep<<<384, 256, 0, stream>>>(support, W, bias, Bsw, Psw);
    k_main<<<128, 512, 0, stream>>>(query, Bsw, Psw, bias, out);
}